// Round 1
// baseline (79431.616 us; speedup 1.0000x reference)
//
#include <hip/hip_runtime.h>
#include <stdint.h>

// ============================================================
// AdaptiveLNN on MI355X, round 9: deep memory-level parallelism.
// r8 counters: VALUBusy 17.8%, HBM 3%, VGPR=56 -> latency-bound weight
// streaming with ~4 loads in flight (compiler targeted 8 waves/SIMD /
// 64-VGPR cap, but 151KB LDS caps us at 1 block/CU = 4 waves/SIMD).
// This round: __launch_bounds__(1024,4) to unlock the 128-VGPR budget,
// and explicit ping-pong register double-buffers (8x uint4 per buffer,
// statically indexed) in matvecF / wrecF so every dot-product phase
// keeps 8-16 weight loads outstanding. Accumulation order unchanged
// (bit-exact vs r8). Everything else identical.
// ============================================================

__device__ __forceinline__ float b2f(unsigned short s){
  union { unsigned i; float f; } c; c.i = ((unsigned)s) << 16; return c.f;
}
__device__ __forceinline__ unsigned short f2b(float f){
  union { unsigned i; float f; } c; c.f = f;
  unsigned r = c.i + 0x7fffu + ((c.i >> 16) & 1u);
  return (unsigned short)(r >> 16);
}
__device__ __forceinline__ unsigned pack2(float a, float b){
  return (unsigned)f2b(a) | ((unsigned)f2b(b) << 16);
}
__device__ __forceinline__ float fsig(float x){ return 1.f/(1.f+__expf(-x)); }
__device__ __forceinline__ float ftanh(float x){ return 1.f - 2.f/(__expf(2.f*x)+1.f); }

#if __has_builtin(__builtin_amdgcn_fdot2_f32_bf16)
typedef __bf16 bf16x2_t __attribute__((ext_vector_type(2)));
__device__ __forceinline__ float dot2(unsigned w, unsigned a, float acc){
  union U { unsigned u; bf16x2_t v; };
  U cw; cw.u = w; U ca; ca.u = a;
  return __builtin_amdgcn_fdot2_f32_bf16(cw.v, ca.v, acc, false);
}
#else
__device__ __forceinline__ float dot2(unsigned w, unsigned a, float acc){
  asm("v_dot2_f32_bf16 %0, %1, %2, %0" : "+v"(acc) : "v"(w), "v"(a));
  return acc;
}
#endif

// ---------- 1024-thread full-dot matvec (scan): o=tid>>1, kh=tid&1 ----------
// Weight layout A: w[(size_t)i*1024 + tid] = 8 bf16 of row o, k-octet 2i+kh.
// Ping-pong double buffer: 8 loads in flight while computing the previous 8.
template<int K, int NOUT>
__device__ __forceinline__ float matvecF(const uint4* __restrict__ w,
                                         const unsigned* __restrict__ act2,
                                         int tid){
  constexpr int NI = K / 16;          // 16 / 32 / 48 / 64
  constexpr int NG = NI / 8;          // 2 / 4 / 6 / 8 (always even)
  static_assert((NG & 1) == 0, "NG must be even");
  const uint4* a4 = (const uint4*)act2;
  const int kh = tid & 1;
  const uint4* wp = w + tid;
  float acc0 = 0.f, acc1 = 0.f;
  uint4 bufA[8], bufB[8];
  #pragma unroll
  for (int j = 0; j < 8; ++j) bufA[j] = wp[(size_t)j * (2*NOUT)];
  #pragma unroll
  for (int g = 0; g < NG; g += 2){
    #pragma unroll
    for (int j = 0; j < 8; ++j) bufB[j] = wp[(size_t)((g+1)*8 + j) * (2*NOUT)];
    #pragma unroll
    for (int j = 0; j < 8; ++j){
      const uint4 a = a4[2*(g*8 + j) + kh];
      acc0 = dot2(bufA[j].x, a.x, acc0);
      acc0 = dot2(bufA[j].y, a.y, acc0);
      acc1 = dot2(bufA[j].z, a.z, acc1);
      acc1 = dot2(bufA[j].w, a.w, acc1);
    }
    if (g + 2 < NG){
      #pragma unroll
      for (int j = 0; j < 8; ++j) bufA[j] = wp[(size_t)((g+2)*8 + j) * (2*NOUT)];
    }
    #pragma unroll
    for (int j = 0; j < 8; ++j){
      const uint4 a = a4[2*((g+1)*8 + j) + kh];
      acc0 = dot2(bufB[j].x, a.x, acc0);
      acc0 = dot2(bufB[j].y, a.y, acc0);
      acc1 = dot2(bufB[j].z, a.z, acc1);
      acc1 = dot2(bufB[j].w, a.w, acc1);
    }
  }
  float acc = acc0 + acc1;
  acc += __shfl_xor(acc, 1);
  return acc;
}

// ---------- Wrec matvec, 9/32 slots LDS-cached (K=512, NOUT=512) ----------
// Streamed slots 9..31 ping-pong double-buffered; LDS slots computed while
// the first streamed group is in flight. Accumulation order = slot order
// 0..31 (identical to r8).
template<bool FILL>
__device__ __forceinline__ float wrecF(const uint4* __restrict__ w,
                                       const unsigned* __restrict__ act2,
                                       uint4* __restrict__ wlds, int tid){
  const uint4* a4 = (const uint4*)act2;
  const int kh = tid & 1;
  const uint4* wp = w + tid;
  float acc0 = 0.f, acc1 = 0.f;
  if (FILL){
    #pragma unroll 3
    for (int i = 0; i < 9; ++i){
      const uint4 wv = wp[(size_t)i*1024];
      wlds[i*1024 + tid] = wv;
      const uint4 a = a4[2*i + kh];
      acc0 = dot2(wv.x, a.x, acc0);
      acc0 = dot2(wv.y, a.y, acc0);
      acc1 = dot2(wv.z, a.z, acc1);
      acc1 = dot2(wv.w, a.w, acc1);
    }
    #pragma unroll 4
    for (int i = 9; i < 32; ++i){
      const uint4 wv = wp[(size_t)i*1024];
      const uint4 a  = a4[2*i + kh];
      acc0 = dot2(wv.x, a.x, acc0);
      acc0 = dot2(wv.y, a.y, acc0);
      acc1 = dot2(wv.z, a.z, acc1);
      acc1 = dot2(wv.w, a.w, acc1);
    }
  } else {
    uint4 S0[8], S1[8];
    // issue streamed slots 9..16
    #pragma unroll
    for (int j = 0; j < 8; ++j) S0[j] = wp[(size_t)(9+j)*1024];
    // compute LDS-cached slots 0..8 while S0 is in flight
    #pragma unroll
    for (int i = 0; i < 9; ++i){
      const uint4 wv = wlds[i*1024 + tid];
      const uint4 a  = a4[2*i + kh];
      acc0 = dot2(wv.x, a.x, acc0);
      acc0 = dot2(wv.y, a.y, acc0);
      acc1 = dot2(wv.z, a.z, acc1);
      acc1 = dot2(wv.w, a.w, acc1);
    }
    // issue streamed slots 17..24
    #pragma unroll
    for (int j = 0; j < 8; ++j) S1[j] = wp[(size_t)(17+j)*1024];
    // compute slots 9..16
    #pragma unroll
    for (int j = 0; j < 8; ++j){
      const uint4 a = a4[2*(9+j) + kh];
      acc0 = dot2(S0[j].x, a.x, acc0);
      acc0 = dot2(S0[j].y, a.y, acc0);
      acc1 = dot2(S0[j].z, a.z, acc1);
      acc1 = dot2(S0[j].w, a.w, acc1);
    }
    // issue streamed slots 25..31
    #pragma unroll
    for (int j = 0; j < 7; ++j) S0[j] = wp[(size_t)(25+j)*1024];
    // compute slots 17..24
    #pragma unroll
    for (int j = 0; j < 8; ++j){
      const uint4 a = a4[2*(17+j) + kh];
      acc0 = dot2(S1[j].x, a.x, acc0);
      acc0 = dot2(S1[j].y, a.y, acc0);
      acc1 = dot2(S1[j].z, a.z, acc1);
      acc1 = dot2(S1[j].w, a.w, acc1);
    }
    // compute slots 25..31
    #pragma unroll
    for (int j = 0; j < 7; ++j){
      const uint4 a = a4[2*(25+j) + kh];
      acc0 = dot2(S0[j].x, a.x, acc0);
      acc0 = dot2(S0[j].y, a.y, acc0);
      acc1 = dot2(S0[j].z, a.z, acc1);
      acc1 = dot2(S0[j].w, a.w, acc1);
    }
  }
  float acc = acc0 + acc1;
  acc += __shfl_xor(acc, 1);
  return acc;
}

// ---------- one LTC layer, one timestep (1024 threads, cached Wrec) ----------
template<int KC, int KI>
__device__ __forceinline__ float layer_stepP(
    float& v, float& g,
    const uint4* Wi, const uint4* Wr, const uint4* Ta, const uint4* Tb,
    float wb, float tab, float tbb, float gl, float gs, float lw, float lb,
    unsigned* comb2, unsigned* thA, unsigned* thB, float* sred,
    uint4* wlds, int tid, bool fill)
{
  float tauh = matvecF<KC, 512>(Ta, comb2, tid);
  float iin  = matvecF<KI, 512>(Wi, comb2, tid) + wb;
  tauh = ftanh(tauh + tab);
  float hv = ftanh(v);
  {
    const float tp = __shfl_down(tauh, 2);
    const float hp = __shfl_down(hv, 2);
    if (!(tid & 3)){ thA[tid >> 2] = pack2(tauh, tp); thB[tid >> 2] = pack2(hv, hp); }
  }
  __syncthreads();                        // thA (tau_h), thB (tanh v) ready
  float tau = matvecF<512, 512>(Tb, thA, tid);
  tau = 0.1f + 9.9f * fsig(tau + tbb);
  const float ga = 0.2f / tau;
  const float va = 0.1f / tau;
  __syncthreads();                        // thA reads done; unfolds may overwrite
  float h = hv;
  #pragma unroll 1
  for (int u = 0; u < 6; ++u){
    unsigned* cur = (u & 1) ? thA : thB;
    unsigned* nxt = (u & 1) ? thB : thA;
    const float irec = (fill && u == 0)
        ? wrecF<true >(Wr, cur, wlds, tid)
        : wrecF<false>(Wr, cur, wlds, tid);
    g += (fsig(iin + irec) - g) * ga;
    v += (gs * g * (1.f - v) - gl * v) * va;
    v = fminf(5.f, fmaxf(-5.f, v));
    h = ftanh(v);
    const float hp = __shfl_down(h, 2);
    if (!(tid & 3)) nxt[tid >> 2] = pack2(h, hp);
    __syncthreads();                      // one barrier per unfold
  }
  // layernorm over 512 outputs (mask duplicate odd lanes)
  const float hm = (tid & 1) ? 0.f : h;
  float s1 = hm, s2 = hm * hm;
  #pragma unroll
  for (int off = 32; off >= 1; off >>= 1){
    s1 += __shfl_down(s1, off);
    s2 += __shfl_down(s2, off);
  }
  const int lane = tid & 63, wid = tid >> 6;
  if (lane == 0){ sred[wid] = s1; sred[16 + wid] = s2; }
  __syncthreads();
  float S1 = 0.f, S2 = 0.f;
  #pragma unroll
  for (int w2 = 0; w2 < 16; ++w2){ S1 += sred[w2]; S2 += sred[16 + w2]; }
  const float m    = S1 * (1.f/512.f);
  const float varr = S2 * (1.f/512.f) - m * m;
  const float y = (h - m) * rsqrtf(varr + 1e-5f) * lw + lb;
  __syncthreads();                        // sred/thA/thB reusable
  return y;
}

// ---------- 512-thread matvec (tail kernels): p=tid>>1, kh=tid&1 ----------
// Weight layout B: w[(ib*NJ+j)*512 + tid] = row j*256+p, k-octet 2ib+kh.
template<int K, int NOUT>
__device__ __forceinline__ void matvec2(const uint4* __restrict__ w,
                                        const unsigned* __restrict__ act2,
                                        int tid, float* out){
  constexpr int NJ = NOUT/256, NIB = K/16;
  const uint4* a4 = (const uint4*)act2;
  const int kh = tid & 1;
  float acc[NJ];
  #pragma unroll
  for (int j = 0; j < NJ; ++j) acc[j] = 0.f;
  #pragma unroll 2
  for (int ib = 0; ib < NIB; ++ib){
    const uint4 a = a4[2*ib + kh];
    #pragma unroll
    for (int j = 0; j < NJ; ++j){
      const uint4 wv = w[(size_t)(ib*NJ + j)*512 + tid];
      acc[j] = dot2(wv.x, a.x, acc[j]);
      acc[j] = dot2(wv.y, a.y, acc[j]);
      acc[j] = dot2(wv.z, a.z, acc[j]);
      acc[j] = dot2(wv.w, a.w, acc[j]);
    }
  }
  #pragma unroll
  for (int j = 0; j < NJ; ++j){
    float s = acc[j];
    s += __shfl_xor(s, 1);
    out[j] = s;
  }
}

// ---------- packed-weight offsets (uint4 units) ----------
#define PK_WIN0   0
#define PK_WREC0  16384
#define PK_TA0    49152
#define PK_TB0    98304
#define PK_WIN1   131072
#define PK_WREC1  163840
#define PK_TA1    196608
#define PK_TB1    262144
#define PK_WQ     294912
#define PK_WK     327680
#define PK_WV     360448
#define PK_AO     393216
#define PK_P1     425984
#define PK_P2     442368
#define PK_TOTAL  450560

// ---------- dtype detection ----------
__global__ void detect_kernel(const unsigned* __restrict__ x, int* __restrict__ flag){
  int cnt = 0;
  for (int i = threadIdx.x; i < 4096; i += 256){
    const unsigned e = (x[i] >> 7) & 0xFFu;
    cnt += (e == 0u || e == 0xFFu) ? 1 : 0;
  }
  __shared__ int sh[4];
  #pragma unroll
  for (int off = 32; off >= 1; off >>= 1) cnt += __shfl_down(cnt, off);
  if ((threadIdx.x & 63) == 0) sh[threadIdx.x >> 6] = cnt;
  __syncthreads();
  if (threadIdx.x == 0) *flag = (sh[0]+sh[1]+sh[2]+sh[3] > 4) ? 1 : 0;
}

// ---------- weight packing (dual dtype, dual layout) ----------
struct PackDesc {
  const void* src[14];
  long eoff[14];
  int kdiv8[14];
  int lg2n[14];
  int mode[14];      // 0 = 1024-thread layout (scan), 1 = 512-thread (tail)
  int cum[15];
};
__global__ void pack_kernel(PackDesc d, const int* __restrict__ flag,
                            uint4* __restrict__ out){
  const int u = blockIdx.x * 256 + threadIdx.x;
  if (u >= d.cum[14]) return;
  int s = 0;
  #pragma unroll
  for (int i = 1; i < 14; ++i) if (u >= d.cum[i]) s = i;
  const int local = u - d.cum[s];
  long base;
  if (d.mode[s] == 0){
    const int ln      = d.lg2n[s];                 // 9
    const int pairIdx = local >> (ln + 1);
    const int rem     = local & ((2 << ln) - 1);
    const int o       = rem >> 1;
    const int kh      = rem & 1;
    const int kb      = pairIdx * 2 + kh;
    base = (long)o * (d.kdiv8[s] * 8) + (long)kb * 8;
  } else {
    const int tid  = local & 511;
    const int r    = local >> 9;
    const int lgnj = d.lg2n[s] - 8;
    const int j    = r & ((1 << lgnj) - 1);
    const int ib   = r >> lgnj;
    const int p    = tid >> 1, kh = tid & 1;
    const int o    = (j << 8) + p;
    base = (long)o * (d.kdiv8[s] * 8) + (long)(2*ib + kh) * 8;
  }
  if (*flag){
    const float* sp = (const float*)d.src[s] + d.eoff[s];
    unsigned short h[8];
    #pragma unroll
    for (int i = 0; i < 8; ++i) h[i] = f2b(sp[base + i]);
    uint4 o4;
    o4.x = (unsigned)h[0] | ((unsigned)h[1] << 16);
    o4.y = (unsigned)h[2] | ((unsigned)h[3] << 16);
    o4.z = (unsigned)h[4] | ((unsigned)h[5] << 16);
    o4.w = (unsigned)h[6] | ((unsigned)h[7] << 16);
    out[u] = o4;
  } else {
    const unsigned short* sp = (const unsigned short*)d.src[s] + d.eoff[s];
    out[u] = *(const uint4*)(sp + base);
  }
}

struct VecDesc {
  const void* src[18];
  int n[18];
  int dst[18];
};
__global__ void vec_kernel(VecDesc d, const int* __restrict__ flag,
                           float* __restrict__ pvec){
  const int s = blockIdx.x;
  const int f = *flag;
  for (int i = threadIdx.x; i < d.n[s]; i += blockDim.x)
    pvec[d.dst[s] + i] = f ? ((const float*)d.src[s])[i]
                           : b2f(((const unsigned short*)d.src[s])[i]);
}

__global__ void zflags_kernel(int* __restrict__ aflag, int* __restrict__ cflag){
  const int i = threadIdx.x;
  if (i < 64) aflag[i] = 0; else cflag[i - 64] = 0;
}

// ---------- layer-pipelined scan: 128 blocks x 1024 threads ----------
#define SCAN_SMEM 151680   // 4224 header + 9*1024*16 Wrec LDS cache
__global__ __launch_bounds__(1024, 4) void scan_kernel(
    const void* __restrict__ xin,
    const uint4* __restrict__ wp,
    const float* __restrict__ pvec,
    const int* __restrict__ flagp,
    unsigned* __restrict__ seqw,
    unsigned* __restrict__ ring,
    int* __restrict__ aflag,
    int* __restrict__ cflag)
{
  extern __shared__ __align__(16) char smem[];
  unsigned* comb2 = (unsigned*)smem;               // 512 uints
  unsigned* thA   = comb2 + 512;                   // 256
  unsigned* thB   = thA + 256;                     // 256
  float*    sred  = (float*)(thB + 256);           // 32 floats
  uint4*    wlds  = (uint4*)(smem + 4224);         // 9*1024 uint4

  const int tid = threadIdx.x;
  const int o   = tid >> 1;
  const int blk = blockIdx.x;
  const int b   = blk & 63;
  const bool isB = blk >= 64;
  const int isf32 = *flagp;
  const int cb  = isB ? 3584 : 0;

  const uint4* Ta = wp + (isB ? PK_TA1  : PK_TA0);
  const uint4* Tb = wp + (isB ? PK_TB1  : PK_TB0);
  const uint4* Wi = wp + (isB ? PK_WIN1 : PK_WIN0);
  const uint4* Wr = wp + (isB ? PK_WREC1: PK_WREC0);

  const float wb  = pvec[cb+o],      tab = pvec[cb+512+o], tbb = pvec[cb+1024+o];
  const float gl  = pvec[cb+1536+o], gs  = pvec[cb+2048+o];
  const float lw  = pvec[cb+2560+o], lb  = pvec[cb+3072+o];

  float v = 0.f, g = 0.f;

  #pragma unroll 1
  for (int t = 0; t < 512; ++t){
    if (!isB){
      // comb2 = [x 128 | v pairs 256]
      if (tid < 128){
        const size_t idx = ((size_t)b*512 + t)*128 + tid;
        if (isf32){
          const float2 xv = ((const float2*)xin)[idx];
          comb2[tid] = pack2(xv.x, xv.y);
        } else {
          comb2[tid] = ((const unsigned*)xin)[idx];
        }
      }
      {
        const float vp = __shfl_down(v, 2);
        if (!(tid & 3)) comb2[128 + (tid >> 2)] = pack2(v, vp);
      }
      __syncthreads();
      const float y = layer_stepP<768, 256>(v, g, Wi, Wr, Ta, Tb,
                                            wb, tab, tbb, gl, gs, lw, lb,
                                            comb2, thA, thB, sred, wlds,
                                            tid, t == 0);
      if (tid == 0 && t >= 8){
        while (__hip_atomic_load(&cflag[b], __ATOMIC_ACQUIRE,
                                 __HIP_MEMORY_SCOPE_AGENT) < t - 7)
          __builtin_amdgcn_s_sleep(1);
      }
      __syncthreads();
      {
        const float yp = __shfl_down(y, 2);
        if (!(tid & 3)){
          unsigned* dst = ring + ((size_t)b*8 + (t & 7))*256;
          __hip_atomic_store(dst + (tid>>2), pack2(y, yp),
                             __ATOMIC_RELAXED, __HIP_MEMORY_SCOPE_AGENT);
        }
      }
      __syncthreads();
      if (tid == 0)
        __hip_atomic_store(&aflag[b], t + 1, __ATOMIC_RELEASE,
                           __HIP_MEMORY_SCOPE_AGENT);
    } else {
      if (tid == 0){
        while (__hip_atomic_load(&aflag[b], __ATOMIC_ACQUIRE,
                                 __HIP_MEMORY_SCOPE_AGENT) < t + 1)
          __builtin_amdgcn_s_sleep(1);
      }
      __syncthreads();
      if (tid < 256){
        const unsigned* src = ring + ((size_t)b*8 + (t & 7))*256;
        comb2[tid] = __hip_atomic_load(src + tid, __ATOMIC_RELAXED,
                                       __HIP_MEMORY_SCOPE_AGENT);
      }
      {
        const float vp = __shfl_down(v, 2);
        if (!(tid & 3)) comb2[256 + (tid >> 2)] = pack2(v, vp);
      }
      __syncthreads();
      if (tid == 0)                       // ring slot consumed -> free it now
        __hip_atomic_store(&cflag[b], t + 1, __ATOMIC_RELEASE,
                           __HIP_MEMORY_SCOPE_AGENT);
      const float y = layer_stepP<1024, 512>(v, g, Wi, Wr, Ta, Tb,
                                             wb, tab, tbb, gl, gs, lw, lb,
                                             comb2, thA, thB, sred, wlds,
                                             tid, t == 0);
      {
        const float yp = __shfl_down(y, 2);
        if (!(tid & 3))
          seqw[((size_t)b*512 + t)*256 + (tid >> 2)] = pack2(y, yp);
      }
    }
  }
}

// ---------- Q projection for t = T-1 ----------
__global__ __launch_bounds__(512) void q_kernel(
    const unsigned* __restrict__ seqw, const uint4* __restrict__ wp,
    const float* __restrict__ pvec, float* __restrict__ qws)
{
  __shared__ __align__(16) unsigned act2[256];
  const int tid = threadIdx.x, b = blockIdx.x, p = tid >> 1;
  if (tid < 256) act2[tid] = seqw[((size_t)(b*512 + 511))*256 + tid];
  __syncthreads();
  float q[2]; matvec2<512, 512>(wp + PK_WQ, act2, tid, q);
  if (!(tid & 1)){
    qws[b*512 + p]       = q[0] + pvec[7168 + p];
    qws[b*512 + 256 + p] = q[1] + pvec[7168 + 256 + p];
  }
}

// ---------- scores: one block per (b,t) ----------
__global__ __launch_bounds__(512) void score_kernel(
    const unsigned* __restrict__ seqw, const uint4* __restrict__ wp,
    const float* __restrict__ pvec, const float* __restrict__ qws,
    float* __restrict__ sws)
{
  __shared__ __align__(16) unsigned act2[256];
  __shared__ float hrA[8], hrB[8];
  const int tid = threadIdx.x, p = tid >> 1;
  const int r = blockIdx.x, b = r >> 9, t = r & 511;
  if (tid < 256) act2[tid] = seqw[(size_t)r*256 + tid];
  __syncthreads();
  float kk[2]; matvec2<512, 512>(wp + PK_WK, act2, tid, kk);
  float pa = (tid & 1) ? 0.f : (kk[0] + pvec[7680 + p])       * qws[b*512 + p];
  float pb = (tid & 1) ? 0.f : (kk[1] + pvec[7680 + 256 + p]) * qws[b*512 + 256 + p];
  #pragma unroll
  for (int off = 32; off >= 1; off >>= 1){
    pa += __shfl_down(pa, off); pb += __shfl_down(pb, off);
  }
  const int lane = tid & 63, wid = tid >> 6;
  if (lane == 0){ hrA[wid] = pa; hrB[wid] = pb; }
  __syncthreads();
  if (tid < 4){
    float s;
    if      (tid == 0) s = hrA[0]+hrA[1]+hrA[2]+hrA[3];
    else if (tid == 1) s = hrA[4]+hrA[5]+hrA[6]+hrA[7];
    else if (tid == 2) s = hrB[0]+hrB[1]+hrB[2]+hrB[3];
    else               s = hrB[4]+hrB[5]+hrB[6]+hrB[7];
    sws[((size_t)(b*4 + tid))*512 + t] = s * 0.08838834764831845f;
  }
}

// ---------- softmax over t per (b,h); zero-init oacc ----------
__global__ __launch_bounds__(512) void softmax_kernel(
    const float* __restrict__ sws, float* __restrict__ pws,
    float* __restrict__ oacc)
{
  __shared__ float rw[16];
  const int tid = threadIdx.x, bh = blockIdx.x;
  const float s = sws[(size_t)bh*512 + tid];
  float mx = s;
  #pragma unroll
  for (int off = 32; off >= 1; off >>= 1) mx = fmaxf(mx, __shfl_down(mx, off));
  const int lane = tid & 63, wid = tid >> 6;
  if (lane == 0) rw[wid] = mx;
  __syncthreads();
  mx = rw[0];
  #pragma unroll
  for (int w2 = 1; w2 < 8; ++w2) mx = fmaxf(mx, rw[w2]);
  const float e = __expf(s - mx);
  float sm = e;
  #pragma unroll
  for (int off = 32; off >= 1; off >>= 1) sm += __shfl_down(sm, off);
  if (lane == 0) rw[8 + wid] = sm;
  __syncthreads();
  sm = 0.f;
  #pragma unroll
  for (int w2 = 0; w2 < 8; ++w2) sm += rw[8 + w2];
  pws[(size_t)bh*512 + tid] = e / sm;
  if (tid < 128) oacc[(bh >> 2)*512 + (bh & 3)*128 + tid] = 0.f;
}

// ---------- V-accumulate: block = (b, 64-t chunk) ----------
__global__ __launch_bounds__(512) void vacc_kernel(
    const unsigned* __restrict__ seqw, const uint4* __restrict__ wp,
    const float* __restrict__ pvec, const float* __restrict__ pws,
    float* __restrict__ oacc)
{
  __shared__ __align__(16) unsigned act2[256];
  const int tid = threadIdx.x, p = tid >> 1;
  const int blk = blockIdx.x, b = blk >> 3, ch = blk & 7;
  float a0 = 0.f, a1 = 0.f;
  #pragma unroll 1
  for (int t = ch*64; t < ch*64 + 64; ++t){
    if (tid < 256) act2[tid] = seqw[((size_t)b*512 + t)*256 + tid];
    __syncthreads();
    float vv[2]; matvec2<512, 512>(wp + PK_WV, act2, tid, vv);
    if (!(tid & 1)){
      a0 += (vv[0] + pvec[8192 + p])       * pws[(size_t)(b*4 + (p>>7))*512 + t];
      a1 += (vv[1] + pvec[8192 + 256 + p]) * pws[(size_t)(b*4 + 2 + (p>>7))*512 + t];
    }
    __syncthreads();
  }
  if (!(tid & 1)){
    atomicAdd(&oacc[b*512 + p], a0);
    atomicAdd(&oacc[b*512 + 256 + p], a1);
  }
}

// ---------- tail ----------
__global__ __launch_bounds__(512) void final_kernel(
    const float* __restrict__ oacc, const uint4* __restrict__ wp,
    const float* __restrict__ pvec, const int* __restrict__ flagp,
    void* __restrict__ out)
{
  __shared__ __align__(16) unsigned a2[256];
  const int tid = threadIdx.x, b = blockIdx.x, p = tid >> 1;
  const int isf32 = *flagp;
  {
    const float x0 = oacc[b*512 + p], x1 = oacc[b*512 + 256 + p];
    const float xa = __shfl_down(x0, 2), xb = __shfl_down(x1, 2);
    if (!(tid & 3)){ a2[tid>>2] = pack2(x0, xa); a2[128+(tid>>2)] = pack2(x1, xb); }
  }
  __syncthreads();
  float t1[2]; matvec2<512, 512>(wp + PK_AO, a2, tid, t1);
  t1[0] += pvec[8704 + p]; t1[1] += pvec[8704 + 256 + p];
  __syncthreads();
  {
    const float ta = __shfl_down(t1[0], 2), tb = __shfl_down(t1[1], 2);
    if (!(tid & 3)){ a2[tid>>2] = pack2(t1[0], ta); a2[128+(tid>>2)] = pack2(t1[1], tb); }
  }
  __syncthreads();
  float t2[1]; matvec2<512, 256>(wp + PK_P1, a2, tid, t2);
  t2[0] = fmaxf(0.f, t2[0] + pvec[9216 + p]);
  __syncthreads();
  {
    const float ta = __shfl_down(t2[0], 2);
    if (!(tid & 3)) a2[tid>>2] = pack2(t2[0], ta);
  }
  __syncthreads();
  float r[1]; matvec2<256, 256>(wp + PK_P2, a2, tid, r);
  if (!(tid & 1)){
    const float rr = r[0] + pvec[9472 + p];
    if (isf32) ((float*)out)[b*256 + p] = rr;
    else       ((unsigned short*)out)[b*256 + p] = f2b(rr);
  }
}

// ---------- fallback if ws too small ----------
__global__ void zero_kernel(unsigned* __restrict__ p, int n){
  const int i = blockIdx.x * 1024 + threadIdx.x;
  if (i < n) p[i] = 0;
}

// ============================================================
extern "C" void kernel_launch(void* const* d_in, const int* in_sizes, int n_in,
                              void* d_out, int out_size, void* d_ws, size_t ws_size,
                              hipStream_t stream)
{
  (void)in_sizes; (void)n_in; (void)out_size;

  if (ws_size < ((size_t)44 << 20)){
    zero_kernel<<<8, 1024, 0, stream>>>((unsigned*)d_out, 8192);
    return;
  }

  hipFuncSetAttribute((const void*)scan_kernel,
                      hipFuncAttributeMaxDynamicSharedMemorySize, SCAN_SMEM);

  char* ws = (char*)d_ws;
  int*      flag   = (int*)ws;
  int*      aflag  = (int*)(ws + 256);
  int*      cflag  = (int*)(ws + 512);
  float*    pvec   = (float*)(ws + 4096);
  uint4*    packed = (uint4*)(ws + 65536);
  unsigned* seq    = (unsigned*)(ws + ((size_t)8 << 20));     // 32 MB
  unsigned* ring   = (unsigned*)(ws + ((size_t)40 << 20));    // 512 KB
  float*    sws    = (float*)(ws + ((size_t)41 << 20));
  float*    pws    = (float*)(ws + ((size_t)41 << 20) + 524288);
  float*    qws    = (float*)(ws + ((size_t)42 << 20));
  float*    oacc   = (float*)(ws + ((size_t)42 << 20) + 262144);

  detect_kernel<<<1, 256, 0, stream>>>((const unsigned*)d_in[0], flag);
  zflags_kernel<<<1, 128, 0, stream>>>(aflag, cflag);

  PackDesc pd;
  const void* msrc[14] = {
    d_in[1], d_in[3], d_in[4], d_in[6],
    d_in[12], d_in[14], d_in[15], d_in[17],
    d_in[23], d_in[23], d_in[23],
    d_in[25], d_in[27], d_in[29]
  };
  const long eoff[14] = {0,0,0,0, 0,0,0,0, 0, 262144, 524288, 0, 0, 0};
  const int kk8[14]  = {32,64,96,64, 64,64,128,64, 64,64,64, 64, 64, 32};
  const int ln2[14]  = {9,9,9,9, 9,9,9,9, 9,9,9, 9, 8, 8};
  const int mode[14] = {0,0,0,0, 0,0,0,0, 1,1,1, 1, 1, 1};
  const int cum[15]  = {0,16384,49152,98304,131072,163840,196608,262144,
                        294912,327680,360448,393216,425984,442368,450560};
  for (int i = 0; i < 14; ++i){
    pd.src[i]=msrc[i]; pd.eoff[i]=eoff[i]; pd.kdiv8[i]=kk8[i];
    pd.lg2n[i]=ln2[i]; pd.mode[i]=mode[i];
  }
  for (int i = 0; i < 15; ++i) pd.cum[i] = cum[i];
  pack_kernel<<<(PK_TOTAL + 255)/256, 256, 0, stream>>>(pd, flag, packed);

  VecDesc vd;
  const void* vsrc[18] = {
    d_in[2], d_in[5], d_in[7], d_in[8], d_in[9], d_in[10], d_in[11],
    d_in[13], d_in[16], d_in[18], d_in[19], d_in[20], d_in[21], d_in[22],
    d_in[24], d_in[26], d_in[28], d_in[30]
  };
  const int vn[18]  = {512,512,512,512,512,512,512, 512,512,512,512,512,512,512,
                       1536,512,256,256};
  const int vds[18] = {0,512,1024,1536,2048,2560,3072,
                       3584,4096,4608,5120,5632,6144,6656,
                       7168,8704,9216,9472};
  for (int i = 0; i < 18; ++i){ vd.src[i]=vsrc[i]; vd.n[i]=vn[i]; vd.dst[i]=vds[i]; }
  vec_kernel<<<18, 512, 0, stream>>>(vd, flag, pvec);

  scan_kernel<<<128, 1024, SCAN_SMEM, stream>>>(d_in[0], packed, pvec, flag,
                                                seq, ring, aflag, cflag);
  q_kernel<<<64, 512, 0, stream>>>(seq, packed, pvec, qws);
  score_kernel<<<64*512, 512, 0, stream>>>(seq, packed, pvec, qws, sws);
  softmax_kernel<<<256, 512, 0, stream>>>(sws, pws, oacc);
  vacc_kernel<<<512, 512, 0, stream>>>(seq, packed, pvec, pws, oacc);
  final_kernel<<<64, 512, 0, stream>>>(oacc, packed, pvec, flag, d_out);
}

// Round 2
// 20976.990 us; speedup vs baseline: 3.7866x; 3.7866x over previous
//
#include <hip/hip_runtime.h>
#include <stdint.h>

// ============================================================
// AdaptiveLNN on MI355X, round 10: fix r9's spill disaster + L2 layering.
// r9 post-mortem: __launch_bounds__(1024,4) only caps VGPR at a minimum-
// occupancy bound; allocator still targeted 8 waves/EU (64 VGPR) and
// spilled the explicit 8+8 uint4 buffers (WRITE_SIZE 67MB->3.9GB = scratch;
// scratch evicted weights from L2 -> FETCH 5.7->58GB, 3x slower).
// r10: (a) amdgpu_waves_per_eu(4,4) pins occupancy at the LDS-forced
// 4 waves/EU so the allocator may use up to 128 VGPRs; matvec bodies
// reverted to r8's spill-proof form (unroll-exposed ILP, no reg arrays).
// (b) XCD-aware block remap: XCDs 0-3 host only layer0 blocks, 4-7 only
// layer1, so each XCD's L2 working set (2.1/2.5MB) fits in 4MB L2
// (was 4.6MB mixed -> thrash at LLC latency).
// ============================================================

__device__ __forceinline__ float b2f(unsigned short s){
  union { unsigned i; float f; } c; c.i = ((unsigned)s) << 16; return c.f;
}
__device__ __forceinline__ unsigned short f2b(float f){
  union { unsigned i; float f; } c; c.f = f;
  unsigned r = c.i + 0x7fffu + ((c.i >> 16) & 1u);
  return (unsigned short)(r >> 16);
}
__device__ __forceinline__ unsigned pack2(float a, float b){
  return (unsigned)f2b(a) | ((unsigned)f2b(b) << 16);
}
__device__ __forceinline__ float fsig(float x){ return 1.f/(1.f+__expf(-x)); }
__device__ __forceinline__ float ftanh(float x){ return 1.f - 2.f/(__expf(2.f*x)+1.f); }

#if __has_builtin(__builtin_amdgcn_fdot2_f32_bf16)
typedef __bf16 bf16x2_t __attribute__((ext_vector_type(2)));
__device__ __forceinline__ float dot2(unsigned w, unsigned a, float acc){
  union U { unsigned u; bf16x2_t v; };
  U cw; cw.u = w; U ca; ca.u = a;
  return __builtin_amdgcn_fdot2_f32_bf16(cw.v, ca.v, acc, false);
}
#else
__device__ __forceinline__ float dot2(unsigned w, unsigned a, float acc){
  asm("v_dot2_f32_bf16 %0, %1, %2, %0" : "+v"(acc) : "v"(w), "v"(a));
  return acc;
}
#endif

// ---------- 1024-thread full-dot matvec (scan): o=tid>>1, kh=tid&1 ----------
// Weight layout A: w[(size_t)i*1024 + tid] = 8 bf16 of row o, k-octet 2i+kh.
template<int K, int NOUT>
__device__ __forceinline__ float matvecF(const uint4* __restrict__ w,
                                         const unsigned* __restrict__ act2,
                                         int tid){
  constexpr int NI = K / 16;
  float acc0 = 0.f, acc1 = 0.f;
  const uint4* a4 = (const uint4*)act2;
  const int kh = tid & 1;
  #pragma unroll 8
  for (int i = 0; i < NI; ++i){
    const uint4 wv = w[(size_t)i*(2*NOUT) + tid];
    const uint4 a  = a4[2*i + kh];
    acc0 = dot2(wv.x, a.x, acc0);
    acc0 = dot2(wv.y, a.y, acc0);
    acc1 = dot2(wv.z, a.z, acc1);
    acc1 = dot2(wv.w, a.w, acc1);
  }
  float acc = acc0 + acc1;
  acc += __shfl_xor(acc, 1);
  return acc;
}

// ---------- Wrec matvec, 9/32 slots LDS-cached (K=512, NOUT=512) ----------
template<bool FILL>
__device__ __forceinline__ float wrecF(const uint4* __restrict__ w,
                                       const unsigned* __restrict__ act2,
                                       uint4* __restrict__ wlds, int tid){
  float acc0 = 0.f, acc1 = 0.f;
  const uint4* a4 = (const uint4*)act2;
  const int kh = tid & 1;
  #pragma unroll 3
  for (int i = 0; i < 9; ++i){
    uint4 wv;
    if (FILL){ wv = w[(size_t)i*1024 + tid]; wlds[i*1024 + tid] = wv; }
    else     { wv = wlds[i*1024 + tid]; }
    const uint4 a = a4[2*i + kh];
    acc0 = dot2(wv.x, a.x, acc0);
    acc0 = dot2(wv.y, a.y, acc0);
    acc1 = dot2(wv.z, a.z, acc1);
    acc1 = dot2(wv.w, a.w, acc1);
  }
  #pragma unroll 8
  for (int i = 9; i < 32; ++i){
    const uint4 wv = w[(size_t)i*1024 + tid];
    const uint4 a  = a4[2*i + kh];
    acc0 = dot2(wv.x, a.x, acc0);
    acc0 = dot2(wv.y, a.y, acc0);
    acc1 = dot2(wv.z, a.z, acc1);
    acc1 = dot2(wv.w, a.w, acc1);
  }
  float acc = acc0 + acc1;
  acc += __shfl_xor(acc, 1);
  return acc;
}

// ---------- one LTC layer, one timestep (1024 threads, cached Wrec) ----------
template<int KC, int KI>
__device__ __forceinline__ float layer_stepP(
    float& v, float& g,
    const uint4* Wi, const uint4* Wr, const uint4* Ta, const uint4* Tb,
    float wb, float tab, float tbb, float gl, float gs, float lw, float lb,
    unsigned* comb2, unsigned* thA, unsigned* thB, float* sred,
    uint4* wlds, int tid, bool fill)
{
  float tauh = matvecF<KC, 512>(Ta, comb2, tid);
  float iin  = matvecF<KI, 512>(Wi, comb2, tid) + wb;
  tauh = ftanh(tauh + tab);
  float hv = ftanh(v);
  {
    const float tp = __shfl_down(tauh, 2);
    const float hp = __shfl_down(hv, 2);
    if (!(tid & 3)){ thA[tid >> 2] = pack2(tauh, tp); thB[tid >> 2] = pack2(hv, hp); }
  }
  __syncthreads();                        // thA (tau_h), thB (tanh v) ready
  float tau = matvecF<512, 512>(Tb, thA, tid);
  tau = 0.1f + 9.9f * fsig(tau + tbb);
  const float ga = 0.2f / tau;
  const float va = 0.1f / tau;
  __syncthreads();                        // thA reads done; unfolds may overwrite
  float h = hv;
  #pragma unroll 1
  for (int u = 0; u < 6; ++u){
    unsigned* cur = (u & 1) ? thA : thB;
    unsigned* nxt = (u & 1) ? thB : thA;
    const float irec = (fill && u == 0)
        ? wrecF<true >(Wr, cur, wlds, tid)
        : wrecF<false>(Wr, cur, wlds, tid);
    g += (fsig(iin + irec) - g) * ga;
    v += (gs * g * (1.f - v) - gl * v) * va;
    v = fminf(5.f, fmaxf(-5.f, v));
    h = ftanh(v);
    const float hp = __shfl_down(h, 2);
    if (!(tid & 3)) nxt[tid >> 2] = pack2(h, hp);
    __syncthreads();                      // one barrier per unfold
  }
  // layernorm over 512 outputs (mask duplicate odd lanes)
  const float hm = (tid & 1) ? 0.f : h;
  float s1 = hm, s2 = hm * hm;
  #pragma unroll
  for (int off = 32; off >= 1; off >>= 1){
    s1 += __shfl_down(s1, off);
    s2 += __shfl_down(s2, off);
  }
  const int lane = tid & 63, wid = tid >> 6;
  if (lane == 0){ sred[wid] = s1; sred[16 + wid] = s2; }
  __syncthreads();
  float S1 = 0.f, S2 = 0.f;
  #pragma unroll
  for (int w2 = 0; w2 < 16; ++w2){ S1 += sred[w2]; S2 += sred[16 + w2]; }
  const float m    = S1 * (1.f/512.f);
  const float varr = S2 * (1.f/512.f) - m * m;
  const float y = (h - m) * rsqrtf(varr + 1e-5f) * lw + lb;
  __syncthreads();                        // sred/thA/thB reusable
  return y;
}

// ---------- 512-thread matvec (tail kernels): p=tid>>1, kh=tid&1 ----------
// Weight layout B: w[(ib*NJ+j)*512 + tid] = row j*256+p, k-octet 2ib+kh.
template<int K, int NOUT>
__device__ __forceinline__ void matvec2(const uint4* __restrict__ w,
                                        const unsigned* __restrict__ act2,
                                        int tid, float* out){
  constexpr int NJ = NOUT/256, NIB = K/16;
  const uint4* a4 = (const uint4*)act2;
  const int kh = tid & 1;
  float acc[NJ];
  #pragma unroll
  for (int j = 0; j < NJ; ++j) acc[j] = 0.f;
  #pragma unroll 2
  for (int ib = 0; ib < NIB; ++ib){
    const uint4 a = a4[2*ib + kh];
    #pragma unroll
    for (int j = 0; j < NJ; ++j){
      const uint4 wv = w[(size_t)(ib*NJ + j)*512 + tid];
      acc[j] = dot2(wv.x, a.x, acc[j]);
      acc[j] = dot2(wv.y, a.y, acc[j]);
      acc[j] = dot2(wv.z, a.z, acc[j]);
      acc[j] = dot2(wv.w, a.w, acc[j]);
    }
  }
  #pragma unroll
  for (int j = 0; j < NJ; ++j){
    float s = acc[j];
    s += __shfl_xor(s, 1);
    out[j] = s;
  }
}

// ---------- packed-weight offsets (uint4 units) ----------
#define PK_WIN0   0
#define PK_WREC0  16384
#define PK_TA0    49152
#define PK_TB0    98304
#define PK_WIN1   131072
#define PK_WREC1  163840
#define PK_TA1    196608
#define PK_TB1    262144
#define PK_WQ     294912
#define PK_WK     327680
#define PK_WV     360448
#define PK_AO     393216
#define PK_P1     425984
#define PK_P2     442368
#define PK_TOTAL  450560

// ---------- dtype detection ----------
__global__ void detect_kernel(const unsigned* __restrict__ x, int* __restrict__ flag){
  int cnt = 0;
  for (int i = threadIdx.x; i < 4096; i += 256){
    const unsigned e = (x[i] >> 7) & 0xFFu;
    cnt += (e == 0u || e == 0xFFu) ? 1 : 0;
  }
  __shared__ int sh[4];
  #pragma unroll
  for (int off = 32; off >= 1; off >>= 1) cnt += __shfl_down(cnt, off);
  if ((threadIdx.x & 63) == 0) sh[threadIdx.x >> 6] = cnt;
  __syncthreads();
  if (threadIdx.x == 0) *flag = (sh[0]+sh[1]+sh[2]+sh[3] > 4) ? 1 : 0;
}

// ---------- weight packing (dual dtype, dual layout) ----------
struct PackDesc {
  const void* src[14];
  long eoff[14];
  int kdiv8[14];
  int lg2n[14];
  int mode[14];      // 0 = 1024-thread layout (scan), 1 = 512-thread (tail)
  int cum[15];
};
__global__ void pack_kernel(PackDesc d, const int* __restrict__ flag,
                            uint4* __restrict__ out){
  const int u = blockIdx.x * 256 + threadIdx.x;
  if (u >= d.cum[14]) return;
  int s = 0;
  #pragma unroll
  for (int i = 1; i < 14; ++i) if (u >= d.cum[i]) s = i;
  const int local = u - d.cum[s];
  long base;
  if (d.mode[s] == 0){
    const int ln      = d.lg2n[s];                 // 9
    const int pairIdx = local >> (ln + 1);
    const int rem     = local & ((2 << ln) - 1);
    const int o       = rem >> 1;
    const int kh      = rem & 1;
    const int kb      = pairIdx * 2 + kh;
    base = (long)o * (d.kdiv8[s] * 8) + (long)kb * 8;
  } else {
    const int tid  = local & 511;
    const int r    = local >> 9;
    const int lgnj = d.lg2n[s] - 8;
    const int j    = r & ((1 << lgnj) - 1);
    const int ib   = r >> lgnj;
    const int p    = tid >> 1, kh = tid & 1;
    const int o    = (j << 8) + p;
    base = (long)o * (d.kdiv8[s] * 8) + (long)(2*ib + kh) * 8;
  }
  if (*flag){
    const float* sp = (const float*)d.src[s] + d.eoff[s];
    unsigned short h[8];
    #pragma unroll
    for (int i = 0; i < 8; ++i) h[i] = f2b(sp[base + i]);
    uint4 o4;
    o4.x = (unsigned)h[0] | ((unsigned)h[1] << 16);
    o4.y = (unsigned)h[2] | ((unsigned)h[3] << 16);
    o4.z = (unsigned)h[4] | ((unsigned)h[5] << 16);
    o4.w = (unsigned)h[6] | ((unsigned)h[7] << 16);
    out[u] = o4;
  } else {
    const unsigned short* sp = (const unsigned short*)d.src[s] + d.eoff[s];
    out[u] = *(const uint4*)(sp + base);
  }
}

struct VecDesc {
  const void* src[18];
  int n[18];
  int dst[18];
};
__global__ void vec_kernel(VecDesc d, const int* __restrict__ flag,
                           float* __restrict__ pvec){
  const int s = blockIdx.x;
  const int f = *flag;
  for (int i = threadIdx.x; i < d.n[s]; i += blockDim.x)
    pvec[d.dst[s] + i] = f ? ((const float*)d.src[s])[i]
                           : b2f(((const unsigned short*)d.src[s])[i]);
}

__global__ void zflags_kernel(int* __restrict__ aflag, int* __restrict__ cflag){
  const int i = threadIdx.x;
  if (i < 64) aflag[i] = 0; else cflag[i - 64] = 0;
}

// ---------- layer-pipelined scan: 128 blocks x 1024 threads ----------
// Block remap: XCD = blockIdx%8 (empirical round-robin). XCDs 0-3 host
// layer0 (batch = (xcd&3)*16 + blockIdx/8), XCDs 4-7 host layer1. Each
// XCD's L2 then holds exactly one layer's weights (2.1/2.5MB < 4MB).
#define SCAN_SMEM 151680   // 4224 header + 9*1024*16 Wrec LDS cache
__global__
__attribute__((amdgpu_flat_work_group_size(1024, 1024), amdgpu_waves_per_eu(4, 4)))
void scan_kernel(
    const void* __restrict__ xin,
    const uint4* __restrict__ wp,
    const float* __restrict__ pvec,
    const int* __restrict__ flagp,
    unsigned* __restrict__ seqw,
    unsigned* __restrict__ ring,
    int* __restrict__ aflag,
    int* __restrict__ cflag)
{
  extern __shared__ __align__(16) char smem[];
  unsigned* comb2 = (unsigned*)smem;               // 512 uints
  unsigned* thA   = comb2 + 512;                   // 256
  unsigned* thB   = thA + 256;                     // 256
  float*    sred  = (float*)(thB + 256);           // 32 floats
  uint4*    wlds  = (uint4*)(smem + 4224);         // 9*1024 uint4

  const int tid = threadIdx.x;
  const int o   = tid >> 1;
  const int blk  = blockIdx.x;
  const int xcd  = blk & 7;                        // empirical XCD id
  const int slot = blk >> 3;                       // 0..15
  const bool isB = xcd >= 4;                       // layer1 on XCDs 4-7
  const int b    = ((xcd & 3) << 4) | slot;        // batch 0..63
  const int isf32 = *flagp;
  const int cb  = isB ? 3584 : 0;

  const uint4* Ta = wp + (isB ? PK_TA1  : PK_TA0);
  const uint4* Tb = wp + (isB ? PK_TB1  : PK_TB0);
  const uint4* Wi = wp + (isB ? PK_WIN1 : PK_WIN0);
  const uint4* Wr = wp + (isB ? PK_WREC1: PK_WREC0);

  const float wb  = pvec[cb+o],      tab = pvec[cb+512+o], tbb = pvec[cb+1024+o];
  const float gl  = pvec[cb+1536+o], gs  = pvec[cb+2048+o];
  const float lw  = pvec[cb+2560+o], lb  = pvec[cb+3072+o];

  float v = 0.f, g = 0.f;

  #pragma unroll 1
  for (int t = 0; t < 512; ++t){
    if (!isB){
      // comb2 = [x 128 | v pairs 256]
      if (tid < 128){
        const size_t idx = ((size_t)b*512 + t)*128 + tid;
        if (isf32){
          const float2 xv = ((const float2*)xin)[idx];
          comb2[tid] = pack2(xv.x, xv.y);
        } else {
          comb2[tid] = ((const unsigned*)xin)[idx];
        }
      }
      {
        const float vp = __shfl_down(v, 2);
        if (!(tid & 3)) comb2[128 + (tid >> 2)] = pack2(v, vp);
      }
      __syncthreads();
      const float y = layer_stepP<768, 256>(v, g, Wi, Wr, Ta, Tb,
                                            wb, tab, tbb, gl, gs, lw, lb,
                                            comb2, thA, thB, sred, wlds,
                                            tid, t == 0);
      if (tid == 0 && t >= 8){
        while (__hip_atomic_load(&cflag[b], __ATOMIC_ACQUIRE,
                                 __HIP_MEMORY_SCOPE_AGENT) < t - 7)
          __builtin_amdgcn_s_sleep(1);
      }
      __syncthreads();
      {
        const float yp = __shfl_down(y, 2);
        if (!(tid & 3)){
          unsigned* dst = ring + ((size_t)b*8 + (t & 7))*256;
          __hip_atomic_store(dst + (tid>>2), pack2(y, yp),
                             __ATOMIC_RELAXED, __HIP_MEMORY_SCOPE_AGENT);
        }
      }
      __syncthreads();
      if (tid == 0)
        __hip_atomic_store(&aflag[b], t + 1, __ATOMIC_RELEASE,
                           __HIP_MEMORY_SCOPE_AGENT);
    } else {
      if (tid == 0){
        while (__hip_atomic_load(&aflag[b], __ATOMIC_ACQUIRE,
                                 __HIP_MEMORY_SCOPE_AGENT) < t + 1)
          __builtin_amdgcn_s_sleep(1);
      }
      __syncthreads();
      if (tid < 256){
        const unsigned* src = ring + ((size_t)b*8 + (t & 7))*256;
        comb2[tid] = __hip_atomic_load(src + tid, __ATOMIC_RELAXED,
                                       __HIP_MEMORY_SCOPE_AGENT);
      }
      {
        const float vp = __shfl_down(v, 2);
        if (!(tid & 3)) comb2[256 + (tid >> 2)] = pack2(v, vp);
      }
      __syncthreads();
      if (tid == 0)                       // ring slot consumed -> free it now
        __hip_atomic_store(&cflag[b], t + 1, __ATOMIC_RELEASE,
                           __HIP_MEMORY_SCOPE_AGENT);
      const float y = layer_stepP<1024, 512>(v, g, Wi, Wr, Ta, Tb,
                                             wb, tab, tbb, gl, gs, lw, lb,
                                             comb2, thA, thB, sred, wlds,
                                             tid, t == 0);
      {
        const float yp = __shfl_down(y, 2);
        if (!(tid & 3))
          seqw[((size_t)b*512 + t)*256 + (tid >> 2)] = pack2(y, yp);
      }
    }
  }
}

// ---------- Q projection for t = T-1 ----------
__global__ __launch_bounds__(512) void q_kernel(
    const unsigned* __restrict__ seqw, const uint4* __restrict__ wp,
    const float* __restrict__ pvec, float* __restrict__ qws)
{
  __shared__ __align__(16) unsigned act2[256];
  const int tid = threadIdx.x, b = blockIdx.x, p = tid >> 1;
  if (tid < 256) act2[tid] = seqw[((size_t)(b*512 + 511))*256 + tid];
  __syncthreads();
  float q[2]; matvec2<512, 512>(wp + PK_WQ, act2, tid, q);
  if (!(tid & 1)){
    qws[b*512 + p]       = q[0] + pvec[7168 + p];
    qws[b*512 + 256 + p] = q[1] + pvec[7168 + 256 + p];
  }
}

// ---------- scores: one block per (b,t) ----------
__global__ __launch_bounds__(512) void score_kernel(
    const unsigned* __restrict__ seqw, const uint4* __restrict__ wp,
    const float* __restrict__ pvec, const float* __restrict__ qws,
    float* __restrict__ sws)
{
  __shared__ __align__(16) unsigned act2[256];
  __shared__ float hrA[8], hrB[8];
  const int tid = threadIdx.x, p = tid >> 1;
  const int r = blockIdx.x, b = r >> 9, t = r & 511;
  if (tid < 256) act2[tid] = seqw[(size_t)r*256 + tid];
  __syncthreads();
  float kk[2]; matvec2<512, 512>(wp + PK_WK, act2, tid, kk);
  float pa = (tid & 1) ? 0.f : (kk[0] + pvec[7680 + p])       * qws[b*512 + p];
  float pb = (tid & 1) ? 0.f : (kk[1] + pvec[7680 + 256 + p]) * qws[b*512 + 256 + p];
  #pragma unroll
  for (int off = 32; off >= 1; off >>= 1){
    pa += __shfl_down(pa, off); pb += __shfl_down(pb, off);
  }
  const int lane = tid & 63, wid = tid >> 6;
  if (lane == 0){ hrA[wid] = pa; hrB[wid] = pb; }
  __syncthreads();
  if (tid < 4){
    float s;
    if      (tid == 0) s = hrA[0]+hrA[1]+hrA[2]+hrA[3];
    else if (tid == 1) s = hrA[4]+hrA[5]+hrA[6]+hrA[7];
    else if (tid == 2) s = hrB[0]+hrB[1]+hrB[2]+hrB[3];
    else               s = hrB[4]+hrB[5]+hrB[6]+hrB[7];
    sws[((size_t)(b*4 + tid))*512 + t] = s * 0.08838834764831845f;
  }
}

// ---------- softmax over t per (b,h); zero-init oacc ----------
__global__ __launch_bounds__(512) void softmax_kernel(
    const float* __restrict__ sws, float* __restrict__ pws,
    float* __restrict__ oacc)
{
  __shared__ float rw[16];
  const int tid = threadIdx.x, bh = blockIdx.x;
  const float s = sws[(size_t)bh*512 + tid];
  float mx = s;
  #pragma unroll
  for (int off = 32; off >= 1; off >>= 1) mx = fmaxf(mx, __shfl_down(mx, off));
  const int lane = tid & 63, wid = tid >> 6;
  if (lane == 0) rw[wid] = mx;
  __syncthreads();
  mx = rw[0];
  #pragma unroll
  for (int w2 = 1; w2 < 8; ++w2) mx = fmaxf(mx, rw[w2]);
  const float e = __expf(s - mx);
  float sm = e;
  #pragma unroll
  for (int off = 32; off >= 1; off >>= 1) sm += __shfl_down(sm, off);
  if (lane == 0) rw[8 + wid] = sm;
  __syncthreads();
  sm = 0.f;
  #pragma unroll
  for (int w2 = 0; w2 < 8; ++w2) sm += rw[8 + w2];
  pws[(size_t)bh*512 + tid] = e / sm;
  if (tid < 128) oacc[(bh >> 2)*512 + (bh & 3)*128 + tid] = 0.f;
}

// ---------- V-accumulate: block = (b, 64-t chunk) ----------
__global__ __launch_bounds__(512) void vacc_kernel(
    const unsigned* __restrict__ seqw, const uint4* __restrict__ wp,
    const float* __restrict__ pvec, const float* __restrict__ pws,
    float* __restrict__ oacc)
{
  __shared__ __align__(16) unsigned act2[256];
  const int tid = threadIdx.x, p = tid >> 1;
  const int blk = blockIdx.x, b = blk >> 3, ch = blk & 7;
  float a0 = 0.f, a1 = 0.f;
  #pragma unroll 1
  for (int t = ch*64; t < ch*64 + 64; ++t){
    if (tid < 256) act2[tid] = seqw[((size_t)b*512 + t)*256 + tid];
    __syncthreads();
    float vv[2]; matvec2<512, 512>(wp + PK_WV, act2, tid, vv);
    if (!(tid & 1)){
      a0 += (vv[0] + pvec[8192 + p])       * pws[(size_t)(b*4 + (p>>7))*512 + t];
      a1 += (vv[1] + pvec[8192 + 256 + p]) * pws[(size_t)(b*4 + 2 + (p>>7))*512 + t];
    }
    __syncthreads();
  }
  if (!(tid & 1)){
    atomicAdd(&oacc[b*512 + p], a0);
    atomicAdd(&oacc[b*512 + 256 + p], a1);
  }
}

// ---------- tail ----------
__global__ __launch_bounds__(512) void final_kernel(
    const float* __restrict__ oacc, const uint4* __restrict__ wp,
    const float* __restrict__ pvec, const int* __restrict__ flagp,
    void* __restrict__ out)
{
  __shared__ __align__(16) unsigned a2[256];
  const int tid = threadIdx.x, b = blockIdx.x, p = tid >> 1;
  const int isf32 = *flagp;
  {
    const float x0 = oacc[b*512 + p], x1 = oacc[b*512 + 256 + p];
    const float xa = __shfl_down(x0, 2), xb = __shfl_down(x1, 2);
    if (!(tid & 3)){ a2[tid>>2] = pack2(x0, xa); a2[128+(tid>>2)] = pack2(x1, xb); }
  }
  __syncthreads();
  float t1[2]; matvec2<512, 512>(wp + PK_AO, a2, tid, t1);
  t1[0] += pvec[8704 + p]; t1[1] += pvec[8704 + 256 + p];
  __syncthreads();
  {
    const float ta = __shfl_down(t1[0], 2), tb = __shfl_down(t1[1], 2);
    if (!(tid & 3)){ a2[tid>>2] = pack2(t1[0], ta); a2[128+(tid>>2)] = pack2(t1[1], tb); }
  }
  __syncthreads();
  float t2[1]; matvec2<512, 256>(wp + PK_P1, a2, tid, t2);
  t2[0] = fmaxf(0.f, t2[0] + pvec[9216 + p]);
  __syncthreads();
  {
    const float ta = __shfl_down(t2[0], 2);
    if (!(tid & 3)) a2[tid>>2] = pack2(t2[0], ta);
  }
  __syncthreads();
  float r[1]; matvec2<256, 256>(wp + PK_P2, a2, tid, r);
  if (!(tid & 1)){
    const float rr = r[0] + pvec[9472 + p];
    if (isf32) ((float*)out)[b*256 + p] = rr;
    else       ((unsigned short*)out)[b*256 + p] = f2b(rr);
  }
}

// ---------- fallback if ws too small ----------
__global__ void zero_kernel(unsigned* __restrict__ p, int n){
  const int i = blockIdx.x * 1024 + threadIdx.x;
  if (i < n) p[i] = 0;
}

// ============================================================
extern "C" void kernel_launch(void* const* d_in, const int* in_sizes, int n_in,
                              void* d_out, int out_size, void* d_ws, size_t ws_size,
                              hipStream_t stream)
{
  (void)in_sizes; (void)n_in; (void)out_size;

  if (ws_size < ((size_t)44 << 20)){
    zero_kernel<<<8, 1024, 0, stream>>>((unsigned*)d_out, 8192);
    return;
  }

  hipFuncSetAttribute((const void*)scan_kernel,
                      hipFuncAttributeMaxDynamicSharedMemorySize, SCAN_SMEM);

  char* ws = (char*)d_ws;
  int*      flag   = (int*)ws;
  int*      aflag  = (int*)(ws + 256);
  int*      cflag  = (int*)(ws + 512);
  float*    pvec   = (float*)(ws + 4096);
  uint4*    packed = (uint4*)(ws + 65536);
  unsigned* seq    = (unsigned*)(ws + ((size_t)8 << 20));     // 32 MB
  unsigned* ring   = (unsigned*)(ws + ((size_t)40 << 20));    // 512 KB
  float*    sws    = (float*)(ws + ((size_t)41 << 20));
  float*    pws    = (float*)(ws + ((size_t)41 << 20) + 524288);
  float*    qws    = (float*)(ws + ((size_t)42 << 20));
  float*    oacc   = (float*)(ws + ((size_t)42 << 20) + 262144);

  detect_kernel<<<1, 256, 0, stream>>>((const unsigned*)d_in[0], flag);
  zflags_kernel<<<1, 128, 0, stream>>>(aflag, cflag);

  PackDesc pd;
  const void* msrc[14] = {
    d_in[1], d_in[3], d_in[4], d_in[6],
    d_in[12], d_in[14], d_in[15], d_in[17],
    d_in[23], d_in[23], d_in[23],
    d_in[25], d_in[27], d_in[29]
  };
  const long eoff[14] = {0,0,0,0, 0,0,0,0, 0, 262144, 524288, 0, 0, 0};
  const int kk8[14]  = {32,64,96,64, 64,64,128,64, 64,64,64, 64, 64, 32};
  const int ln2[14]  = {9,9,9,9, 9,9,9,9, 9,9,9, 9, 8, 8};
  const int mode[14] = {0,0,0,0, 0,0,0,0, 1,1,1, 1, 1, 1};
  const int cum[15]  = {0,16384,49152,98304,131072,163840,196608,262144,
                        294912,327680,360448,393216,425984,442368,450560};
  for (int i = 0; i < 14; ++i){
    pd.src[i]=msrc[i]; pd.eoff[i]=eoff[i]; pd.kdiv8[i]=kk8[i];
    pd.lg2n[i]=ln2[i]; pd.mode[i]=mode[i];
  }
  for (int i = 0; i < 15; ++i) pd.cum[i] = cum[i];
  pack_kernel<<<(PK_TOTAL + 255)/256, 256, 0, stream>>>(pd, flag, packed);

  VecDesc vd;
  const void* vsrc[18] = {
    d_in[2], d_in[5], d_in[7], d_in[8], d_in[9], d_in[10], d_in[11],
    d_in[13], d_in[16], d_in[18], d_in[19], d_in[20], d_in[21], d_in[22],
    d_in[24], d_in[26], d_in[28], d_in[30]
  };
  const int vn[18]  = {512,512,512,512,512,512,512, 512,512,512,512,512,512,512,
                       1536,512,256,256};
  const int vds[18] = {0,512,1024,1536,2048,2560,3072,
                       3584,4096,4608,5120,5632,6144,6656,
                       7168,8704,9216,9472};
  for (int i = 0; i < 18; ++i){ vd.src[i]=vsrc[i]; vd.n[i]=vn[i]; vd.dst[i]=vds[i]; }
  vec_kernel<<<18, 512, 0, stream>>>(vd, flag, pvec);

  scan_kernel<<<128, 1024, SCAN_SMEM, stream>>>(d_in[0], packed, pvec, flag,
                                                seq, ring, aflag, cflag);
  q_kernel<<<64, 512, 0, stream>>>(seq, packed, pvec, qws);
  score_kernel<<<64*512, 512, 0, stream>>>(seq, packed, pvec, qws, sws);
  softmax_kernel<<<256, 512, 0, stream>>>(sws, pws, oacc);
  vacc_kernel<<<512, 512, 0, stream>>>(sws == 0 ? 0 : seq, packed, pvec, pws, oacc);
  final_kernel<<<64, 512, 0, stream>>>(oacc, packed, pvec, flag, d_out);
}